// Round 1
// baseline (327.751 us; speedup 1.0000x reference)
//
#include <hip/hip_runtime.h>
#include <math.h>

#define BB 32
#define LL 50
#define CC 80
#define AA 3
#define IMGF 480.0f
#define ROWS_TOTAL 14175
#define BOX_OFF 1L
#define SCORE_OFF (1L + (long)BB * ROWS_TOTAL * 4)   // 1814401 floats

// cells per image per level
#define CB0 10800
#define CB1 2700
#define CB2 675
#define NCELLS (BB * (CB0 + CB1 + CB2))   // 453600

// 64 cells per block (256 threads, 4 threads/cell)
#define CH0 169
#define CH1 43
#define CH2 11
#define BLK0 (BB * CH0)   // 5408
#define BLK1 (BB * CH1)   // 1376
#define BLK2 (BB * CH2)   // 352
#define NBLK (BLK0 + BLK1 + BLK2)   // 7136

// workspace layout (byte offsets, all 16B-aligned)
#define WS_MATCH 0                         // int[453600]
#define WS_CREC  (NCELLS * 4)              // float[32*50*8] compacted GT records
#define WS_NVAL  (WS_CREC + BB * LL * 8 * 4)   // int[32]
#define WS_ADJ   (WS_NVAL + 128)           // float[3*32*50*5] adjusted targets
#define WS_PART  (WS_ADJ + 3 * BB * LL * 5 * 4) // float[NBLK] block partials

// ---------------------------------------------------------------------------
// init: fill match table with -1; compact valid GT boxes per image
// record: [tminx, tminy, tmaxx, tmaxy, 0.6*area, pad, pad, pad]  (normalized)
// ---------------------------------------------------------------------------
__global__ void init_kernel(const float* __restrict__ gt, char* __restrict__ ws)
{
    int idx = blockIdx.x * blockDim.x + threadIdx.x;
    int4* mt = (int4*)(ws + WS_MATCH);
    if (idx < NCELLS / 4) mt[idx] = make_int4(-1, -1, -1, -1);
    if (blockIdx.x == 0 && threadIdx.x < BB) {
        int b = threadIdx.x;
        float* cr = (float*)(ws + WS_CREC) + b * LL * 8;
        int n = 0;
        for (int t = 0; t < LL; ++t) {
            const float* g = gt + (b * LL + t) * 5;
            float x = g[0], y = g[1], w = g[2], h = g[3];
            if (w > 0.0f) {
                float* r = cr + n * 8;
                r[0] = x - 0.5f * w; r[1] = y - 0.5f * h;
                r[2] = x + 0.5f * w; r[3] = y + 0.5f * h;
                r[4] = 0.6f * (w * h); r[5] = 0.f; r[6] = 0.f; r[7] = 0.f;
                n++;
            }
        }
        ((int*)(ws + WS_NVAL))[b] = n;
    }
}

// ---------------------------------------------------------------------------
// prep: per (level,b,t) valid GT: adjusted targets + atomicMax scatter into
// the match table (max t == last-write-wins of the reference scatter).
// ---------------------------------------------------------------------------
__global__ void prep_kernel(const float* __restrict__ gt,
                            const float* __restrict__ anchors,
                            char* __restrict__ ws)
{
    int idx = blockIdx.x * blockDim.x + threadIdx.x;
    if (idx >= 3 * BB * LL) return;
    int t   = idx % LL;
    int b   = (idx / LL) % BB;
    int lvl = idx / (LL * BB);
    int W       = (lvl == 0) ? 60 : (lvl == 1) ? 30 : 15;
    int cells_b = (lvl == 0) ? CB0 : (lvl == 1) ? CB1 : CB2;
    int cellof  = (lvl == 0) ? 0 : (lvl == 1) ? BB * CB0 : BB * (CB0 + CB1);
    float Wf = (float)W;

    const float* g = gt + (b * LL + t) * 5;
    float x = g[0], y = g[1], wd = g[2], ht = g[3], cls = g[4];
    if (wd <= 0.0f) return;
    float bx = x * Wf, by = y * Wf, bw = wd * Wf, bh = ht * Wf;
    int j = min(max((int)floorf(bx), 0), W - 1);
    int i = min(max((int)floorf(by), 0), W - 1);

    float best = -1.0f; int k = 0; float kaw = 1.0f, kah = 1.0f;
#pragma unroll
    for (int kk = 0; kk < AA; ++kk) {
        float aw = anchors[kk * 2 + 0] * Wf;
        float ah = anchors[kk * 2 + 1] * Wf;
        float inter = fminf(bw, aw) * fminf(bh, ah);
        float iou = inter / (bw * bh + aw * ah - inter + 1e-9f);
        if (iou > best) { best = iou; k = kk; kaw = aw; kah = ah; }
    }
    int cell = (i * W + j) * AA + k;
    atomicMax((int*)(ws + WS_MATCH) + cellof + b * cells_b + cell, t);
    float* ad = (float*)(ws + WS_ADJ) + ((lvl * BB + b) * LL + t) * 5;
    ad[0] = bx - (float)j;
    ad[1] = by - (float)i;
    ad[2] = logf(bw / kaw);
    ad[3] = logf(bh / kah);
    ad[4] = cls;
}

// ---------------------------------------------------------------------------
// main: all three levels. 4 threads/cell, 64 cells/block.
// NEW: LDS-staged, fully-coalesced aligned streaming:
//   - preds slab (64 cells x 85 fl, contiguous) loaded via aligned float4 stream
//   - GT records staged to LDS once per block (ignore loop reads LDS)
//   - scores computed into LDS [64][80] tile, streamed out as aligned float4
//     with 3-float head to absorb the +1-float global layout misalignment
// ---------------------------------------------------------------------------
__global__ __launch_bounds__(256) void main_kernel(
    const float* __restrict__ preds0,
    const float* __restrict__ preds1,
    const float* __restrict__ preds2,
    const float* __restrict__ anchors,
    const char* __restrict__ wsc,
    float* __restrict__ partials,
    float* __restrict__ out)
{
    __shared__ __align__(16) float lds[5448];      // preds slab, reused for scores
    __shared__ __align__(16) float gtrec[LL * 8];  // 400 floats
    __shared__ float red[4];

    const int*   matchtbl = (const int*)(wsc + WS_MATCH);
    const float* crec     = (const float*)(wsc + WS_CREC);
    const int*   nval     = (const int*)(wsc + WS_NVAL);
    const float* adj      = (const float*)(wsc + WS_ADJ);

    int bid = blockIdx.x;
    const float* preds; int W, cells_b, rowoff, cellof, b, chunk, lvl;
    float invW; unsigned Wmagic;
    if (bid < BLK0) {
        lvl = 0; preds = preds0; W = 60; invW = 1.0f / 60.0f; Wmagic = 71582789u;
        cells_b = CB0; rowoff = 0; cellof = 0;
        b = bid / CH0; chunk = bid - b * CH0;
    } else if (bid < BLK0 + BLK1) {
        int inner = bid - BLK0;
        lvl = 1; preds = preds1; W = 30; invW = 1.0f / 30.0f; Wmagic = 143165577u;
        cells_b = CB1; rowoff = CB0; cellof = BB * CB0;
        b = inner / CH1; chunk = inner - b * CH1;
    } else {
        int inner = bid - BLK0 - BLK1;
        lvl = 2; preds = preds2; W = 15; invW = 1.0f / 15.0f; Wmagic = 286331154u;
        cells_b = CB2; rowoff = CB0 + CB1; cellof = BB * (CB0 + CB1);
        b = inner / CH2; chunk = inner - b * CH2;
    }

    int tid = threadIdx.x;
    int g   = tid >> 2;
    int sub = tid & 3;
    int ncell = cells_b - chunk * 64; if (ncell > 64) ncell = 64;
    bool cvalid = g < ncell;
    int lc = cvalid ? g : (ncell - 1);        // clamped local cell
    int cellg = chunk * 64 + lc;              // clamped global cell (within image)

    // ---- stage preds slab -> LDS (aligned coalesced float4 stream) ----
    long S = ((long)b * cells_b + chunk * 64) * 85;   // first float of slab
    int off0 = (int)(S & 3);
    long Sa = S - off0;                                // 16B-aligned float index
    int nf = off0 + ncell * 85;                        // floats to stage
    int n4 = nf >> 2;
    const float4* s4 = (const float4*)(preds + Sa);
    for (int i = tid; i < n4; i += 256) ((float4*)lds)[i] = s4[i];
    if (tid < (nf & 3)) lds[(n4 << 2) + tid] = preds[Sa + (n4 << 2) + tid];

    // ---- stage GT records -> LDS ----
    if (tid < 100) ((float4*)gtrec)[tid] = ((const float4*)(crec + b * LL * 8))[tid];

    int wt = matchtbl[cellof + b * cells_b + cellg];
    int nv = nval[b];
    __syncthreads();

    // ---- LDS -> registers ----
    int base = off0 + lc * 85;
    float f0 = lds[base + 0], f1 = lds[base + 1], f2 = lds[base + 2];
    float f3 = lds[base + 3], f4 = lds[base + 4];
    float q[20];
#pragma unroll
    for (int k = 0; k < 5; ++k)
#pragma unroll
        for (int j = 0; j < 4; ++j)
            q[4 * k + j] = lds[base + 5 + 4 * sub + 16 * k + j];
    __syncthreads();   // slab now free for score reuse

    // ---- softmax numerators + sum over the cell's quad ----
#pragma unroll
    for (int k = 0; k < 20; ++k) q[k] = __expf(q[k]);
    float s = 0.0f;
#pragma unroll
    for (int k = 0; k < 20; ++k) s += q[k];
    s += __shfl_xor(s, 1);
    s += __shfl_xor(s, 2);
    float invs = __builtin_amdgcn_rcpf(s);

    float conf = __builtin_amdgcn_rcpf(1.0f + __expf(-f4));
    float bxs  = __builtin_amdgcn_rcpf(1.0f + __expf(-f0));
    float bys  = __builtin_amdgcn_rcpf(1.0f + __expf(-f1));

    // geometry
    int t1 = cellg / 3;
    int a  = cellg - t1 * 3;
    int hh = (int)__umulhi((unsigned)t1, Wmagic);
    int ww = t1 - hh * W;
    float ancw = anchors[2 * a], anch = anchors[2 * a + 1];
    float pw = __expf(f2) * ancw;
    float ph = __expf(f3) * anch;
    float px = (bxs + (float)ww) * invW;
    float py = (bys + (float)hh) * invW;
    float pminx = px - 0.5f * pw, pmaxx = px + 0.5f * pw;
    float pminy = py - 0.5f * ph, pmaxy = py + 0.5f * ph;
    float pa06 = 0.6f * (pw * ph) + 0.6e-9f;

    // ---- ignore test from LDS GT records ----
    float amax = -1.0f;
    for (int t = sub; t < nv; t += 4) {
        const float* r = gtrec + t * 8;
        float ix = fmaxf(fminf(pmaxx, r[2]) - fmaxf(pminx, r[0]), 0.0f);
        float iy = fmaxf(fminf(pmaxy, r[3]) - fmaxf(pminy, r[1]), 0.0f);
        amax = fmaxf(amax, 1.6f * (ix * iy) - (pa06 + r[4]));
    }
    unsigned long long bal = __ballot(amax > 0.0f);
    bool objdet = ((bal >> (tid & 60)) & 0xFULL) != 0ULL;

    // ---- losses ----
    float partial = 0.0f;
    if (cvalid) {
        if (wt >= 0) {
            const float* ar = adj + ((lvl * BB + b) * LL + wt) * 5;
            int label = (int)ar[4];
            int c = 4 * sub;
#pragma unroll
            for (int k = 0; k < 5; ++k)
#pragma unroll
                for (int j = 0; j < 4; ++j) {
                    float d = ((c + 16 * k + j) == label ? 1.0f : 0.0f)
                            - q[4 * k + j] * invs;
                    partial += d * d;
                }
            if (sub == 0) {
                float c0 = ar[0] - bxs, c1 = ar[1] - bys;
                float c2 = ar[2] - f2,  c3 = ar[3] - f3;
                partial += c0 * c0 + c1 * c1 + c2 * c2 + c3 * c3;   // coord
                float u = 1.0f - conf;
                partial += 5.0f * u * u;                            // obj
            }
        } else if (sub == 0) {
            partial += (objdet ? 0.0f : 1.0f) * conf * conf;        // noobj
        }
    }

    // ---- scores into LDS tile [64][80] (16B-aligned ds_write_b128) ----
    float ci = conf * invs;
    if (cvalid) {
        float* srow = lds + g * 80 + 4 * sub;
#pragma unroll
        for (int k = 0; k < 5; ++k) {
            float4 o = make_float4(q[4 * k + 0] * ci, q[4 * k + 1] * ci,
                                   q[4 * k + 2] * ci, q[4 * k + 3] * ci);
            *(float4*)(srow + 16 * k) = o;
        }
        // boxes: per-lane dword stream (already fully coalesced)
        long rb = (long)b * ROWS_TOTAL + rowoff + cellg;
        float comp = (sub == 0) ? pminx : (sub == 1) ? pminy
                   : (sub == 2) ? pmaxx : pmaxy;
        out[BOX_OFF + rb * 4 + sub] = comp * IMGF;
    }

    // per-wave loss reduce
    float vsum = partial;
#pragma unroll
    for (int off = 32; off; off >>= 1) vsum += __shfl_xor(vsum, off);
    if ((tid & 63) == 0) red[tid >> 6] = vsum;
    __syncthreads();   // scores tile + red[] ready

    // ---- stream scores LDS -> global (aligned float4 body) ----
    int rbase = b * ROWS_TOTAL + rowoff + chunk * 64;
    float* gdst = out + SCORE_OFF + (long)rbase * CC;   // float index == 1 (mod 4)
    int nfs = ncell * 80;
    if (tid < 3) gdst[tid] = lds[tid];                  // head: reach 16B boundary
    int nbody = (nfs - 3) >> 2;
    float4* d4 = (float4*)(gdst + 3);
    for (int i = tid; i < nbody; i += 256) {
        int j = 3 + (i << 2);
        d4[i] = make_float4(lds[j], lds[j + 1], lds[j + 2], lds[j + 3]);
    }
    int tailo = 3 + (nbody << 2);
    if (tid < (nfs - tailo)) gdst[tailo + tid] = lds[tailo + tid];

    if (tid == 0) partials[bid] = 0.5f * (red[0] + red[1] + red[2] + red[3]);
}

__global__ void reduce_kernel(const float* __restrict__ partials,
                              float* __restrict__ out)
{
    __shared__ float red[4];
    float s = 0.0f;
    for (int i = threadIdx.x; i < NBLK; i += 256) s += partials[i];
#pragma unroll
    for (int off = 32; off; off >>= 1) s += __shfl_xor(s, off);
    int wave = threadIdx.x >> 6;
    if ((threadIdx.x & 63) == 0) red[wave] = s;
    __syncthreads();
    if (threadIdx.x == 0) out[0] = red[0] + red[1] + red[2] + red[3];
}

extern "C" void kernel_launch(void* const* d_in, const int* in_sizes, int n_in,
                              void* d_out, int out_size, void* d_ws, size_t ws_size,
                              hipStream_t stream)
{
    const float* preds0  = (const float*)d_in[0];
    const float* preds1  = (const float*)d_in[1];
    const float* preds2  = (const float*)d_in[2];
    const float* gt      = (const float*)d_in[3];
    const float* anchors = (const float*)d_in[4];
    float* out = (float*)d_out;
    char* ws = (char*)d_ws;

    init_kernel<<<(NCELLS / 4 + 255) / 256, 256, 0, stream>>>(gt, ws);
    prep_kernel<<<(3 * BB * LL + 255) / 256, 256, 0, stream>>>(gt, anchors, ws);
    main_kernel<<<NBLK, 256, 0, stream>>>(preds0, preds1, preds2, anchors,
                                          (const char*)ws,
                                          (float*)(ws + WS_PART), out);
    reduce_kernel<<<1, 256, 0, stream>>>((const float*)(ws + WS_PART), out);
}